// Round 4
// baseline (314.491 us; speedup 1.0000x reference)
//
#include <hip/hip_runtime.h>
#include <math.h>

// Problem constants (from reference)
#define Bn 8
#define Hn 32
#define Dn 128
#define Cn 4096
#define PSn 128
#define NCHUNK 32
#define CHUNK 128   // positions per attention wave == one page

// -------------------- batch-8 GEMV, outer-product form ----------------------
// Block = 8 output cols x 8 batch rows. 4 waves; wave w owns c-quarter.
// 64 accumulators (8r x 8o) per wave, 8x8 outer product per float4 step.
// gridDim.y selects the matrix (fused q/k/v); y output stride Bn*Cn.
extern "C" __global__ __launch_bounds__(256) void gemv8(
    const float* __restrict__ xin,
    const float* __restrict__ W0, const float* __restrict__ b0,
    const float* __restrict__ W1, const float* __restrict__ b1,
    const float* __restrict__ W2, const float* __restrict__ b2,
    float* __restrict__ ybase)
{
    const int m    = blockIdx.y;
    const float* W    = (m == 0) ? W0 : ((m == 1) ? W1 : W2);
    const float* bias = (m == 0) ? b0 : ((m == 1) ? b1 : b2);
    float* y = ybase + (size_t)m * (Bn * Cn);

    const int wv   = threadIdx.x >> 6;   // wave 0..3 -> c-quarter
    const int lane = threadIdx.x & 63;
    const int obase = blockIdx.x * 8;

    float acc[8][8];
#pragma unroll
    for (int r = 0; r < 8; ++r)
#pragma unroll
        for (int j = 0; j < 8; ++j) acc[r][j] = 0.f;

    const float* wp = W + (size_t)obase * Cn;
#pragma unroll
    for (int it = 0; it < 4; ++it) {
        const int c = wv * 1024 + it * 256 + lane * 4;
        float4 w4[8], x4[8];
#pragma unroll
        for (int j = 0; j < 8; ++j) w4[j] = *(const float4*)(wp + (size_t)j * Cn + c);
#pragma unroll
        for (int r = 0; r < 8; ++r) x4[r] = *(const float4*)(xin + (size_t)r * Cn + c);
#pragma unroll
        for (int r = 0; r < 8; ++r)
#pragma unroll
            for (int j = 0; j < 8; ++j) {
                acc[r][j] = fmaf(x4[r].x, w4[j].x,
                            fmaf(x4[r].y, w4[j].y,
                            fmaf(x4[r].z, w4[j].z,
                            fmaf(x4[r].w, w4[j].w, acc[r][j]))));
            }
    }

    // Per-wave butterfly; lane (r*8+j) keeps sum (r,j).
    const int lr = lane >> 3, lj = lane & 7;
    float mine = 0.f;
#pragma unroll
    for (int r = 0; r < 8; ++r)
#pragma unroll
        for (int j = 0; j < 8; ++j) {
            float v = acc[r][j];
#pragma unroll
            for (int off = 32; off; off >>= 1) v += __shfl_xor(v, off);
            if (lr == r && lj == j) mine = v;
        }

    __shared__ float red[4][64];
    red[wv][lane] = mine;
    __syncthreads();
    if (threadIdx.x < 64) {
        const float s = red[0][lane] + red[1][lane] + red[2][lane] + red[3][lane]
                      + bias[obase + lj];
        y[(size_t)lr * Cn + obase + lj] = s;
    }
}

// -------------------- single-pass flash-decode attention --------------------
// One WAVE per (chunk,h,b); chunk == page (128 rows). No LDS, no barriers.
// Two 32-lane groups per wave; per group-iteration: K-row dot + butterfly
// reduce + online-softmax update + V-row accumulate. Groups merged via
// shfl_xor(32). Position cur substitutes freshly projected k/v (wave-uniform
// branch; only chunk==cur>>7 waves take the per-iter select path).
extern "C" __global__ __launch_bounds__(256) void attn_flash(
    const float* __restrict__ kp, const float* __restrict__ vp,
    const float* __restrict__ qn, const float* __restrict__ kn,
    const float* __restrict__ vn, const int* __restrict__ curp,
    float* __restrict__ pout, float* __restrict__ pml)
{
    const int wv    = threadIdx.x >> 6;
    const int lane  = threadIdx.x & 63;
    const int l32   = lane & 31;
    const int sg    = lane >> 5;                 // group 0/1
    const int chunk = blockIdx.x * 4 + wv;       // 0..31 == page index
    const int h = blockIdx.y, b = blockIdx.z;
    const int cur = *curp;

    const float4 q4 = *(const float4*)(qn + (size_t)b * Cn + h * Dn + l32 * 4);
    const size_t pgstride = (size_t)Bn * Hn * PSn * Dn;
    const size_t slice    = (((size_t)b * Hn + h) * PSn) * (size_t)Dn;
    const float* kpg  = kp + (size_t)chunk * pgstride + slice;
    const float* vpg  = vp + (size_t)chunk * pgstride + slice;
    const float* newk = kn + (size_t)b * Cn + h * Dn;
    const float* newv = vn + (size_t)b * Cn + h * Dn;
    const bool has_cur = ((cur >> 7) == chunk);
    const float scale = 0.08838834764831845f;    // 1/sqrt(128)

    float m = -1e30f, l = 0.f;
    float4 acc = make_float4(0.f, 0.f, 0.f, 0.f);

    if (!has_cur) {
#pragma unroll 4
        for (int it = 0; it < 64; ++it) {
            const int r = it * 2 + sg;
            const float4 k4 = *(const float4*)(kpg + (size_t)r * Dn + l32 * 4);
            const float4 v4 = *(const float4*)(vpg + (size_t)r * Dn + l32 * 4);
            float d = fmaf(k4.x,q4.x, fmaf(k4.y,q4.y, fmaf(k4.z,q4.z, k4.w*q4.w)));
#pragma unroll
            for (int off = 16; off; off >>= 1) d += __shfl_xor(d, off);
            const float s  = d * scale;
            const float mn = fmaxf(m, s);
            const float c  = __expf(m - mn);
            const float p  = __expf(s - mn);
            l = fmaf(l, c, p);
            acc.x = fmaf(acc.x, c, p * v4.x);
            acc.y = fmaf(acc.y, c, p * v4.y);
            acc.z = fmaf(acc.z, c, p * v4.z);
            acc.w = fmaf(acc.w, c, p * v4.w);
            m = mn;
        }
    } else {
#pragma unroll 2
        for (int it = 0; it < 64; ++it) {
            const int r = it * 2 + sg;
            const int s_glob = chunk * CHUNK + r;
            const float* krow = (s_glob == cur) ? newk : (kpg + (size_t)r * Dn);
            const float* vrow = (s_glob == cur) ? newv : (vpg + (size_t)r * Dn);
            const float4 k4 = *(const float4*)(krow + l32 * 4);
            const float4 v4 = *(const float4*)(vrow + l32 * 4);
            float d = fmaf(k4.x,q4.x, fmaf(k4.y,q4.y, fmaf(k4.z,q4.z, k4.w*q4.w)));
#pragma unroll
            for (int off = 16; off; off >>= 1) d += __shfl_xor(d, off);
            const float s  = d * scale;
            const float mn = fmaxf(m, s);
            const float c  = __expf(m - mn);
            const float p  = __expf(s - mn);
            l = fmaf(l, c, p);
            acc.x = fmaf(acc.x, c, p * v4.x);
            acc.y = fmaf(acc.y, c, p * v4.y);
            acc.z = fmaf(acc.z, c, p * v4.z);
            acc.w = fmaf(acc.w, c, p * v4.w);
            m = mn;
        }
    }

    // Merge the two 32-lane groups across the half-wave boundary.
    const float mo = __shfl_xor(m, 32);
    const float mn = fmaxf(m, mo);
    const float c  = __expf(m - mn);
    l *= c; acc.x *= c; acc.y *= c; acc.z *= c; acc.w *= c;
    l     += __shfl_xor(l, 32);
    acc.x += __shfl_xor(acc.x, 32);
    acc.y += __shfl_xor(acc.y, 32);
    acc.z += __shfl_xor(acc.z, 32);
    acc.w += __shfl_xor(acc.w, 32);

    const int head = b * Hn + h;
    if (sg == 0) {
        *(float4*)(pout + ((size_t)head * NCHUNK + chunk) * Dn + l32 * 4) = acc;
        if (l32 == 0) {
            pml[(head * NCHUNK + chunk) * 2 + 0] = mn;
            pml[(head * NCHUNK + chunk) * 2 + 1] = l;
        }
    }
}

// -------------------- combine partials --------------------------------------
extern "C" __global__ __launch_bounds__(128) void attn_combine(
    const float* __restrict__ pout, const float* __restrict__ pml,
    float* __restrict__ aout)
{
    const int head = blockIdx.x;   // 0..255 = b*H + h
    const int tid  = threadIdx.x;  // 0..127 = d
    __shared__ float ml[NCHUNK * 2];
    if (tid < NCHUNK * 2) ml[tid] = pml[head * NCHUNK * 2 + tid];
    __syncthreads();
    float mstar = -1e30f;
#pragma unroll
    for (int i = 0; i < NCHUNK; ++i) mstar = fmaxf(mstar, ml[2 * i]);
    float L = 0.f, acc = 0.f;
#pragma unroll 8
    for (int i = 0; i < NCHUNK; ++i) {
        const float w = __expf(ml[2 * i] - mstar);
        L   += ml[2 * i + 1] * w;
        acc += w * pout[((size_t)head * NCHUNK + i) * Dn + tid];
    }
    aout[(size_t)head * Dn + tid] = acc / L;
}

// -------------------- launch -------------------------------------------------
extern "C" void kernel_launch(void* const* d_in, const int* in_sizes, int n_in,
                              void* d_out, int out_size, void* d_ws, size_t ws_size,
                              hipStream_t stream)
{
    const float* x  = (const float*)d_in[0];
    const float* kp = (const float*)d_in[1];
    const float* vp = (const float*)d_in[2];
    const float* Wq = (const float*)d_in[3];
    const float* bq = (const float*)d_in[4];
    const float* Wk = (const float*)d_in[5];
    const float* bk = (const float*)d_in[6];
    const float* Wv = (const float*)d_in[7];
    const float* bv = (const float*)d_in[8];
    const float* Wo = (const float*)d_in[9];
    const float* bo = (const float*)d_in[10];
    const int* curp = (const int*)d_in[11];

    // ws layout (floats): q | k_new | v_new | pout | pml | attn_out  (~4.6 MB)
    float* ws   = (float*)d_ws;
    float* q    = ws;                // 32768
    float* kn   = ws + 32768;        // 32768
    float* vn   = ws + 65536;        // 32768
    float* pout = ws + 98304;        // 256*32*128 = 1048576
    float* pml  = ws + 1146880;      // 256*32*2   = 16384
    float* aout = ws + 1163264;      // 32768
    float* dout = (float*)d_out;

    gemv8<<<dim3(512, 3), 256, 0, stream>>>(x, Wq, bq, Wk, bk, Wv, bv, q);
    attn_flash<<<dim3(NCHUNK / 4, Hn, Bn), 256, 0, stream>>>(kp, vp, q, kn, vn, curp, pout, pml);
    attn_combine<<<256, 128, 0, stream>>>(pout, pml, aout);
    gemv8<<<dim3(512, 1), 256, 0, stream>>>(aout, Wo, bo, Wo, bo, Wo, bo, dout);
}

// Round 6
// 241.994 us; speedup vs baseline: 1.2996x; 1.2996x over previous
//
#include <hip/hip_runtime.h>
#include <math.h>

// Problem constants (from reference)
#define Bn 8
#define Hn 32
#define Dn 128
#define Cn 4096
#define PSn 128
#define NCHUNK 8
#define CHUNK 512   // positions per attention block (spans 4 pages)

// clang ext-vector float4 (usable with __builtin_nontemporal_load)
typedef float f4 __attribute__((ext_vector_type(4)));

// -------------------- batch-8 GEMV, outer-product form ----------------------
// Block = 8 output cols x 8 batch rows. 4 waves; wave w owns c-quarter.
// 64 accumulators (8r x 8o) per wave, 8x8 outer product per float4 step.
// gridDim.y selects the matrix (fused q/k/v); y output stride Bn*Cn.
extern "C" __global__ __launch_bounds__(256) void gemv8(
    const float* __restrict__ xin,
    const float* __restrict__ W0, const float* __restrict__ b0,
    const float* __restrict__ W1, const float* __restrict__ b1,
    const float* __restrict__ W2, const float* __restrict__ b2,
    float* __restrict__ ybase)
{
    const int m    = blockIdx.y;
    const float* W    = (m == 0) ? W0 : ((m == 1) ? W1 : W2);
    const float* bias = (m == 0) ? b0 : ((m == 1) ? b1 : b2);
    float* y = ybase + (size_t)m * (Bn * Cn);

    const int wv   = threadIdx.x >> 6;   // wave 0..3 -> c-quarter
    const int lane = threadIdx.x & 63;
    const int obase = blockIdx.x * 8;

    float acc[8][8];
#pragma unroll
    for (int r = 0; r < 8; ++r)
#pragma unroll
        for (int j = 0; j < 8; ++j) acc[r][j] = 0.f;

    const float* wp = W + (size_t)obase * Cn;
#pragma unroll
    for (int it = 0; it < 4; ++it) {
        const int c = wv * 1024 + it * 256 + lane * 4;
        float4 w4[8], x4[8];
#pragma unroll
        for (int j = 0; j < 8; ++j) w4[j] = *(const float4*)(wp + (size_t)j * Cn + c);
#pragma unroll
        for (int r = 0; r < 8; ++r) x4[r] = *(const float4*)(xin + (size_t)r * Cn + c);
#pragma unroll
        for (int r = 0; r < 8; ++r)
#pragma unroll
            for (int j = 0; j < 8; ++j) {
                acc[r][j] = fmaf(x4[r].x, w4[j].x,
                            fmaf(x4[r].y, w4[j].y,
                            fmaf(x4[r].z, w4[j].z,
                            fmaf(x4[r].w, w4[j].w, acc[r][j]))));
            }
    }

    // Per-wave butterfly; lane (r*8+j) keeps sum (r,j).
    const int lr = lane >> 3, lj = lane & 7;
    float mine = 0.f;
#pragma unroll
    for (int r = 0; r < 8; ++r)
#pragma unroll
        for (int j = 0; j < 8; ++j) {
            float v = acc[r][j];
#pragma unroll
            for (int off = 32; off; off >>= 1) v += __shfl_xor(v, off);
            if (lr == r && lj == j) mine = v;
        }

    __shared__ float red[4][64];
    red[wv][lane] = mine;
    __syncthreads();
    if (threadIdx.x < 64) {
        const float s = red[0][lane] + red[1][lane] + red[2][lane] + red[3][lane]
                      + bias[obase + lj];
        y[(size_t)lr * Cn + obase + lj] = s;
    }
}

// -------------------- flash-decode partial attention ------------------------
// grid (NCHUNK, H, B), 256 threads, CHUNK=512 rows per block (4 pages).
// Phase 1: 8 groups of 32 lanes stream K rows (nt loads) + shuffle-reduce
// dots into sc[512]. Block softmax partial (m,l). Phase 2: stream V rows,
// accumulate float4 per group, LDS cross-group reduce. cur substitution is a
// uniform per-block branch (only the block containing cur takes selects).
extern "C" __global__ __launch_bounds__(256) void attn_partial(
    const float* __restrict__ kp, const float* __restrict__ vp,
    const float* __restrict__ qn, const float* __restrict__ kn,
    const float* __restrict__ vn, const int* __restrict__ curp,
    float* __restrict__ pout, float* __restrict__ pml)
{
    const int chunk = blockIdx.x, h = blockIdx.y, b = blockIdx.z;
    const int tid = threadIdx.x;
    const int cur = *curp;

    __shared__ float  sc[CHUNK];
    __shared__ float  wred[8];
    __shared__ float4 red[8][32];

    const int l32 = tid & 31;
    const int g   = tid >> 5;           // 0..7
    const float4 q4   = *(const float4*)(qn + (size_t)b * Cn + h * Dn + l32 * 4);
    const float* newk = kn + (size_t)b * Cn + h * Dn;
    const float* newv = vn + (size_t)b * Cn + h * Dn;
    const int s0 = chunk * CHUNK;
    const float* kbase = kp + (((size_t)b * Hn + h) * PSn) * (size_t)Dn;
    const float* vbase = vp + (((size_t)b * Hn + h) * PSn) * (size_t)Dn;
    const size_t pgstride = (size_t)Bn * Hn * PSn * Dn;
    const bool has_cur = (cur >= s0) && (cur < s0 + CHUNK);

    // Phase 1: scores (K stream)
    if (!has_cur) {
#pragma unroll 8
        for (int it = 0; it < CHUNK / 8; ++it) {
            const int sl = it * 8 + g;
            const int s  = s0 + sl;
            const float* krow = kbase + (size_t)(s >> 7) * pgstride + (size_t)(s & 127) * Dn;
            const f4 k4 = __builtin_nontemporal_load((const f4*)(krow + l32 * 4));
            float d = fmaf(q4.x,k4.x, fmaf(q4.y,k4.y, fmaf(q4.z,k4.z, q4.w*k4.w)));
#pragma unroll
            for (int off = 16; off; off >>= 1) d += __shfl_xor(d, off);
            if (l32 == 0) sc[sl] = d * 0.08838834764831845f;
        }
    } else {
#pragma unroll 4
        for (int it = 0; it < CHUNK / 8; ++it) {
            const int sl = it * 8 + g;
            const int s  = s0 + sl;
            const float* krow = (s == cur) ? newk
                : kbase + (size_t)(s >> 7) * pgstride + (size_t)(s & 127) * Dn;
            const f4 k4 = __builtin_nontemporal_load((const f4*)(krow + l32 * 4));
            float d = fmaf(q4.x,k4.x, fmaf(q4.y,k4.y, fmaf(q4.z,k4.z, q4.w*k4.w)));
#pragma unroll
            for (int off = 16; off; off >>= 1) d += __shfl_xor(d, off);
            if (l32 == 0) sc[sl] = d * 0.08838834764831845f;
        }
    }
    __syncthreads();

    // block softmax partial (m, l) over 512 scores, 2 per thread
    float e0 = sc[tid], e1 = sc[tid + 256];
    float m = fmaxf(e0, e1);
#pragma unroll
    for (int off = 32; off; off >>= 1) m = fmaxf(m, __shfl_xor(m, off));
    if ((tid & 63) == 0) wred[tid >> 6] = m;
    __syncthreads();
    m = fmaxf(fmaxf(wred[0], wred[1]), fmaxf(wred[2], wred[3]));
    const float p0 = __expf(e0 - m);
    const float p1 = __expf(e1 - m);
    sc[tid] = p0;
    sc[tid + 256] = p1;
    float l = p0 + p1;
#pragma unroll
    for (int off = 32; off; off >>= 1) l += __shfl_xor(l, off);
    if ((tid & 63) == 0) wred[4 + (tid >> 6)] = l;
    __syncthreads();
    const float lsum = wred[4] + wred[5] + wred[6] + wred[7];

    // Phase 2: out_partial[d] = sum_s p[s] * v[s,d]  (V stream)
    const int d4 = tid & 31;
    const int sg = tid >> 5;
    float4 acc = make_float4(0.f, 0.f, 0.f, 0.f);
    if (!has_cur) {
#pragma unroll 8
        for (int it = 0; it < CHUNK / 8; ++it) {
            const int sl = it * 8 + sg;
            const int s  = s0 + sl;
            const float* vrow = vbase + (size_t)(s >> 7) * pgstride + (size_t)(s & 127) * Dn;
            const f4 v4 = __builtin_nontemporal_load((const f4*)(vrow + d4 * 4));
            const float pw = sc[sl];
            acc.x = fmaf(pw, v4.x, acc.x);
            acc.y = fmaf(pw, v4.y, acc.y);
            acc.z = fmaf(pw, v4.z, acc.z);
            acc.w = fmaf(pw, v4.w, acc.w);
        }
    } else {
#pragma unroll 4
        for (int it = 0; it < CHUNK / 8; ++it) {
            const int sl = it * 8 + sg;
            const int s  = s0 + sl;
            const float* vrow = (s == cur) ? newv
                : vbase + (size_t)(s >> 7) * pgstride + (size_t)(s & 127) * Dn;
            const f4 v4 = __builtin_nontemporal_load((const f4*)(vrow + d4 * 4));
            const float pw = sc[sl];
            acc.x = fmaf(pw, v4.x, acc.x);
            acc.y = fmaf(pw, v4.y, acc.y);
            acc.z = fmaf(pw, v4.z, acc.z);
            acc.w = fmaf(pw, v4.w, acc.w);
        }
    }
    red[sg][d4] = acc;
    __syncthreads();
    const int head = b * Hn + h;
    if (tid < 32) {
        float4 o = make_float4(0.f, 0.f, 0.f, 0.f);
#pragma unroll
        for (int i = 0; i < 8; ++i) {
            const float4 t = red[i][tid];
            o.x += t.x; o.y += t.y; o.z += t.z; o.w += t.w;
        }
        float* dst = pout + ((size_t)(head * NCHUNK + chunk)) * Dn + tid * 4;
        *(float4*)dst = o;
    }
    if (tid == 0) {
        pml[(head * NCHUNK + chunk) * 2 + 0] = m;
        pml[(head * NCHUNK + chunk) * 2 + 1] = lsum;
    }
}

// -------------------- combine partials --------------------------------------
extern "C" __global__ __launch_bounds__(128) void attn_combine(
    const float* __restrict__ pout, const float* __restrict__ pml,
    float* __restrict__ aout)
{
    const int head = blockIdx.x;   // 0..255 = b*H + h
    const int tid  = threadIdx.x;  // 0..127 = d
    __shared__ float ml[NCHUNK * 2];
    if (tid < NCHUNK * 2) ml[tid] = pml[head * NCHUNK * 2 + tid];
    __syncthreads();
    float mstar = -1e30f;
#pragma unroll
    for (int i = 0; i < NCHUNK; ++i) mstar = fmaxf(mstar, ml[2 * i]);
    float L = 0.f, acc = 0.f;
#pragma unroll
    for (int i = 0; i < NCHUNK; ++i) {
        const float w = __expf(ml[2 * i] - mstar);
        L   += ml[2 * i + 1] * w;
        acc += w * pout[((size_t)head * NCHUNK + i) * Dn + tid];
    }
    aout[(size_t)head * Dn + tid] = acc / L;
}

// -------------------- launch -------------------------------------------------
extern "C" void kernel_launch(void* const* d_in, const int* in_sizes, int n_in,
                              void* d_out, int out_size, void* d_ws, size_t ws_size,
                              hipStream_t stream)
{
    const float* x  = (const float*)d_in[0];
    const float* kp = (const float*)d_in[1];
    const float* vp = (const float*)d_in[2];
    const float* Wq = (const float*)d_in[3];
    const float* bq = (const float*)d_in[4];
    const float* Wk = (const float*)d_in[5];
    const float* bk = (const float*)d_in[6];
    const float* Wv = (const float*)d_in[7];
    const float* bv = (const float*)d_in[8];
    const float* Wo = (const float*)d_in[9];
    const float* bo = (const float*)d_in[10];
    const int* curp = (const int*)d_in[11];

    // ws layout (floats): q | k_new | v_new | pout | pml | attn_out
    float* ws   = (float*)d_ws;
    float* q    = ws;               // 32768
    float* kn   = ws + 32768;       // 32768
    float* vn   = ws + 65536;       // 32768
    float* pout = ws + 98304;       // 256*8*128 = 262144
    float* pml  = ws + 360448;      // 256*8*2   = 4096
    float* aout = ws + 364544;      // 32768
    float* dout = (float*)d_out;

    gemv8<<<dim3(512, 3), 256, 0, stream>>>(x, Wq, bq, Wk, bk, Wv, bv, q);
    attn_partial<<<dim3(NCHUNK, Hn, Bn), 256, 0, stream>>>(kp, vp, q, kn, vn, curp, pout, pml);
    attn_combine<<<256, 128, 0, stream>>>(pout, pml, aout);
    gemv8<<<dim3(512, 1), 256, 0, stream>>>(aout, Wo, bo, Wo, bo, Wo, bo, dout);
}